// Round 10
// baseline (176.825 us; speedup 1.0000x reference)
//
#include <hip/hip_runtime.h>
#include <math.h>

#define B_ 16
#define T_ 2048
#define D_ 256
#define W_ 128
#define M_ (B_*T_)   // 32768

typedef __attribute__((ext_vector_type(8))) short bf16x8;
typedef __attribute__((ext_vector_type(4))) float f32x4;
typedef unsigned short u16;

static __device__ __forceinline__ u16 f32_bf16_rne(float f) {
    unsigned int u = __float_as_uint(f);
    u += 0x7FFF + ((u >> 16) & 1);
    return (u16)(u >> 16);
}
static __device__ __forceinline__ float bf16_f32(u16 h) {
    return __uint_as_float(((unsigned int)h) << 16);
}
// async global->LDS, 16B per lane.  LDS dest = wave-uniform base + lane*16.
static __device__ __forceinline__ void gload_lds16(const u16* g, u16* l) {
    __builtin_amdgcn_global_load_lds(
        (const __attribute__((address_space(1))) void*)g,
        (__attribute__((address_space(3))) void*)l, 16, 0, 0);
}

// ---------------------------------------------------------------------------
// K0: transpose weights to bf16 [mat][n][k] via LDS tile (coalesced both
// sides).  hi for all 4 mats; lo for Wk only.  Grid (4 mats, 16 tiles 64x64).
// ---------------------------------------------------------------------------
__global__ __launch_bounds__(256) void aft_split_wT(
    const float* __restrict__ Wq, const float* __restrict__ Wk,
    const float* __restrict__ Wv, const float* __restrict__ Wo,
    u16* __restrict__ Wth, u16* __restrict__ Wkl)
{
    __shared__ alignas(16) u16 Th[64][72];
    __shared__ alignas(16) u16 Tl[64][72];
    const float* Ws[4] = {Wq, Wk, Wv, Wo};
    const int mat = blockIdx.x;
    const float* W = Ws[mat];
    const int k0 = (blockIdx.y & 3) * 64;
    const int n0 = (blockIdx.y >> 2) * 64;
    const int tid = threadIdx.x;

    #pragma unroll
    for (int p = 0; p < 4; ++p) {
        const int k = p * 16 + (tid >> 4);
        const int n = (tid & 15) * 4;
        float4 v = *(const float4*)&W[(size_t)(k0 + k) * 256 + n0 + n];
        float vv[4] = {v.x, v.y, v.z, v.w};
        #pragma unroll
        for (int e = 0; e < 4; ++e) {
            u16 h = f32_bf16_rne(vv[e]);
            Th[n + e][k] = h;
            Tl[n + e][k] = f32_bf16_rne(vv[e] - bf16_f32(h));
        }
    }
    __syncthreads();

    const int n  = tid >> 2;
    const int kc = (tid & 3) * 16;
    size_t ob = ((size_t)mat * 256 + n0 + n) * 256 + k0 + kc;
    *(uint4*)&Wth[ob]     = *(const uint4*)&Th[n][kc];
    *(uint4*)&Wth[ob + 8] = *(const uint4*)&Th[n][kc + 8];
    if (mat == 1) {
        size_t ol = ((size_t)(n0 + n)) * 256 + k0 + kc;
        *(uint4*)&Wkl[ol]     = *(const uint4*)&Tl[n][kc];
        *(uint4*)&Wkl[ol + 8] = *(const uint4*)&Tl[n][kc + 8];
    }
}

// ---------------------------------------------------------------------------
// K0b: banded EW precompute. EWb[t][j], j in [0,320): exp(wb[t][s])-1 inside
// band else 0, s = (t & ~63) - 128 + j.  bf16.
// ---------------------------------------------------------------------------
__global__ void aft_ewb(const float* __restrict__ wb, u16* __restrict__ EWb)
{
    const int t = blockIdx.x;
    const int j = threadIdx.x;   // blockDim = 320
    const int s = (t & ~63) - 128 + j;
    const int dlt = s - t;
    float v = 0.f;
    if (s >= 0 && s < T_ && dlt > -W_ && dlt < W_)
        v = expf(wb[(size_t)t * T_ + s]) - 1.0f;
    EWb[(size_t)t * 320 + j] = f32_bf16_rne(v);
}

// ---------------------------------------------------------------------------
// K1: QKV projections (R5/R7 main loop, measured plateau 46.5us).  Epilogue
// also emits per-(row, t-block) partial sums of ek/ekv into Skp (f32).
// R10: Skp layout transposed to [tblk][row] -- the R9 [row][tblk] layout made
// 64 lanes write 4B each at 128B stride (full-line traffic: WRITE_SIZE
// 49->57MB for a 1MB logical write).  Now 64 consecutive floats per store.
// ---------------------------------------------------------------------------
__global__ __launch_bounds__(256, 3) void aft_qkv_mfma(
    const float* __restrict__ x,
    const u16* __restrict__ Wth, const u16* __restrict__ Wkl,
    u16* __restrict__ ekT, u16* __restrict__ sigqT, float* __restrict__ Skp)
{
    // main loop: Ah[64][32] + Al[64][32] + Bs[4][64][32] = 12288 u16 (24KB)
    // epilogue:  Tr[64][72] = 4608 u16 reuses the same space
    __shared__ alignas(16) u16 sm[12288];
    u16* Ah = sm;               // [64][32]
    u16* Al = sm + 2048;        // [64][32]
    u16* Bs = sm + 4096;        // [4][64][32]: Wqh, Wkh, Wkl, Wvh
    u16* Tr = sm;               // [64][72] epilogue reuse

    const int tid  = threadIdx.x;
    const int row0 = blockIdx.x * 64;
    const int col0 = blockIdx.y * 64;
    const int b    = row0 >> 11;
    const int t0g  = row0 & (T_ - 1);
    const int tblk = blockIdx.x & 31;    // t-block index within batch b
    const int lane = tid & 63;
    const int wid  = tid >> 6;           // 0..3
    const int wm   = (wid >> 1) * 32;    // 2 M-groups of 32
    const int wn   = (wid & 1) * 32;     // 2 N-groups of 32
    const int qd   = lane >> 4;
    const int r    = lane & 15;

    f32x4 accq[2][2], acck[2][2], accv[2][2];
    #pragma unroll
    for (int i = 0; i < 2; ++i)
        #pragma unroll
        for (int j = 0; j < 2; ++j) {
            accq[i][j] = (f32x4){0.f, 0.f, 0.f, 0.f};
            acck[i][j] = accq[i][j];
            accv[i][j] = accq[i][j];
        }

    // staging coords: 256 threads cover 64 rows x 32 cols (4 chunks of 8 u16)
    const int crow  = tid >> 2;                 // 0..63
    const int gchk  = tid & 3;                  // this thread's global chunk
    const int cswz  = (crow >> 1) & 3;          // row-dependent chunk XOR
    const int ccols = (gchk ^ cswz) * 8;        // pre-swizzled SOURCE col (B)
    const int aslot = crow * 32 + (gchk ^ cswz) * 8;  // swizzled LDS slot (A)
    const int wbase = wid * 512;                // gload dest: wave chunk (u16)
    // fragment-read slot with the matching XOR (verified R3: conflicts ~0)
    const int sq8   = (qd ^ ((r >> 1) & 3)) * 8;

    for (int k0 = 0; k0 < D_; k0 += 32) {
        if (k0) __syncthreads();          // compute(k-1) reads done
        // stage B: 4 tensors x 64 rows, linear dest + swizzled source
        {
            size_t gb = (size_t)(col0 + crow) * 256 + k0 + ccols;
            gload_lds16(&Wth[gb],          &Bs[0 * 2048 + wbase]);
            gload_lds16(&Wth[65536 + gb],  &Bs[1 * 2048 + wbase]);
            gload_lds16(&Wkl[gb],          &Bs[2 * 2048 + wbase]);
            gload_lds16(&Wth[131072 + gb], &Bs[3 * 2048 + wbase]);
        }
        // stage A: x fp32 -> bf16 hi/lo in-register -> swizzled ds_write
        // (source col UNswizzled gchk*8, dest slot swizzled -- rule #21)
        {
            size_t ga = (size_t)(row0 + crow) * 256 + k0 + gchk * 8;
            float4 v0 = *(const float4*)&x[ga];
            float4 v1 = *(const float4*)&x[ga + 4];
            float vv[8] = {v0.x, v0.y, v0.z, v0.w, v1.x, v1.y, v1.z, v1.w};
            union { uint4 q; u16 h[8]; } H, L;
            #pragma unroll
            for (int e = 0; e < 8; ++e) {
                u16 h = f32_bf16_rne(vv[e]);
                H.h[e] = h;
                L.h[e] = f32_bf16_rne(vv[e] - bf16_f32(h));
            }
            *(uint4*)&Ah[aslot] = H.q;
            *(uint4*)&Al[aslot] = L.q;
        }
        __syncthreads();                  // drains vmcnt (B) + lgkm (A writes)

        bf16x8 ah[2], al[2];
        #pragma unroll
        for (int mf = 0; mf < 2; ++mf) {
            int ar = (wm + mf * 16 + r) * 32 + sq8;
            ah[mf] = *(const bf16x8*)&Ah[ar];
            al[mf] = *(const bf16x8*)&Al[ar];
        }
        #pragma unroll
        for (int nf = 0; nf < 2; ++nf) {
            int br = (wn + nf * 16 + r) * 32 + sq8;
            bf16x8 bq  = *(const bf16x8*)&Bs[br];
            bf16x8 bkh = *(const bf16x8*)&Bs[2048 + br];
            bf16x8 bkl = *(const bf16x8*)&Bs[4096 + br];
            bf16x8 bv  = *(const bf16x8*)&Bs[6144 + br];
            #pragma unroll
            for (int mf = 0; mf < 2; ++mf) {
                accq[mf][nf] = __builtin_amdgcn_mfma_f32_16x16x32_bf16(ah[mf], bq,  accq[mf][nf], 0, 0, 0);
                acck[mf][nf] = __builtin_amdgcn_mfma_f32_16x16x32_bf16(ah[mf], bkh, acck[mf][nf], 0, 0, 0);
                acck[mf][nf] = __builtin_amdgcn_mfma_f32_16x16x32_bf16(ah[mf], bkl, acck[mf][nf], 0, 0, 0);
                acck[mf][nf] = __builtin_amdgcn_mfma_f32_16x16x32_bf16(al[mf], bkh, acck[mf][nf], 0, 0, 0);
                accv[mf][nf] = __builtin_amdgcn_mfma_f32_16x16x32_bf16(ah[mf], bv,  accv[mf][nf], 0, 0, 0);
            }
        }
    }

    // epilogue: 3 LDS-transpose rounds (ek, ekv, sigq) -> global bf16.
    // rounds 0/1 also emit f32 partial row-sums (over this block's 64 t).
    const int dl_r = tid >> 2;            // 0..63
    const int tseg = (tid & 3) * 16;      // 0..48
    #pragma unroll
    for (int round = 0; round < 3; ++round) {
        __syncthreads();
        #pragma unroll
        for (int mf = 0; mf < 2; ++mf) {
            #pragma unroll
            for (int nf = 0; nf < 2; ++nf) {
                ushort4 o;
                float vals[4];
                #pragma unroll
                for (int reg = 0; reg < 4; ++reg) {
                    if (round == 0)      vals[reg] = expf(acck[mf][nf][reg]);
                    else if (round == 1) vals[reg] = expf(acck[mf][nf][reg]) * accv[mf][nf][reg];
                    else                 vals[reg] = 1.f / (1.f + expf(-accq[mf][nf][reg]));
                }
                o.x = f32_bf16_rne(vals[0]); o.y = f32_bf16_rne(vals[1]);
                o.z = f32_bf16_rne(vals[2]); o.w = f32_bf16_rne(vals[3]);
                int dl = wn + nf * 16 + r;
                int tt = wm + mf * 16 + qd * 4;
                *(ushort4*)&Tr[dl * 72 + tt] = o;
            }
        }
        __syncthreads();
        u16* dst;
        if (round == 0)      dst = ekT   + ((size_t)(b * 512 + col0 + dl_r)) * 2048;
        else if (round == 1) dst = ekT   + ((size_t)(b * 512 + 256 + col0 + dl_r)) * 2048;
        else                 dst = sigqT + ((size_t)(b * 256 + col0 + dl_r)) * 2048;
        dst += t0g + tseg;
        const u16* srcp = &Tr[dl_r * 72 + tseg];
        uint4 q0 = *(const uint4*)&srcp[0];
        uint4 q1 = *(const uint4*)&srcp[8];
        *(uint4*)&dst[0] = q0;
        *(uint4*)&dst[8] = q1;
        if (round < 2) {
            const u16* h0 = (const u16*)&q0;
            const u16* h1 = (const u16*)&q1;
            float s = 0.f;
            #pragma unroll
            for (int i = 0; i < 8; ++i) s += bf16_f32(h0[i]);
            #pragma unroll
            for (int i = 0; i < 8; ++i) s += bf16_f32(h1[i]);
            s += __shfl_down(s, 1, 64);   // 4 threads per row -> tree reduce
            s += __shfl_down(s, 2, 64);
            if ((tid & 3) == 0)
                Skp[(size_t)tblk * 8192 + (b * 512 + round * 256 + col0 + dl_r)] = s;
        }
    }
}

// ---------------------------------------------------------------------------
// K2: reduce K1's partials (1MB) -> Sk (n<256), Sv (n>=256).  R10: Skp is
// [tblk][row], so each tblk-iteration reads 256 consecutive floats
// (coalesced).  Same ascending-tblk summation order as R9 (bit-identical).
// ---------------------------------------------------------------------------
__global__ __launch_bounds__(256) void aft_sums2(
    const float* __restrict__ Skp, float* __restrict__ Sk, float* __restrict__ Sv)
{
    const int row = blockIdx.x * 256 + threadIdx.x;   // 0..8191
    float s = 0.f;
    #pragma unroll 8
    for (int c = 0; c < 32; ++c)
        s += Skp[(size_t)c * 8192 + row];
    const int b = row >> 9, n = row & 511;
    if (n < 256) Sk[b * 256 + n] = s;
    else         Sv[b * 256 + n - 256] = s;
}

// ---------------------------------------------------------------------------
// K3: banded num/den via bf16 MFMA.  128-t tile (512 thr, 8 waves 2tx4d) --
// band redundancy 3x.  Wave tile 64t x 32d (acc 64 regs).  B (ek/ekv) via
// gload_lds (swizzled source); A (EWb) via reg+ds_write (UNswizzled source,
// swizzled dest -- rule #21, R9 fix).  Epilogue: y = sig(q)*(Sv+num)/(Sk+den).
// ---------------------------------------------------------------------------
__global__ __launch_bounds__(512, 4) void aft_band_mfma(
    const u16* __restrict__ EWb, const u16* __restrict__ ekT,
    const u16* __restrict__ sigqT,
    const float* __restrict__ Sk, const float* __restrict__ Sv,
    u16* __restrict__ yTD)
{
    // main: Aw[128][32] @0 (4096 u16) + Bkv[256][32] @4096 (8192 u16)
    // epilogue: Ly[128][136] = 17408 u16 (34KB) reuses the whole span
    __shared__ alignas(16) u16 sm[17408];
    u16* Aw  = sm;            // [128][32] swizzled
    u16* Bkv = sm + 4096;     // [256][32]: rows 0..127 ek, 128..255 ekv

    const int tid  = threadIdx.x;        // 0..511
    const int t0   = blockIdx.x * 128;
    const int b    = blockIdx.y >> 1;
    const int dh   = (blockIdx.y & 1) * 128;
    const int lane = tid & 63;
    const int wid  = tid >> 6;           // 0..7
    const int th   = wid >> 2;           // t-half (0/1)
    const int wn   = (wid & 3) * 32;     // d-quarter
    const int qd   = lane >> 4;
    const int r    = lane & 15;

    f32x4 accn[4][2], accd[4][2];        // 64 VGPRs
    #pragma unroll
    for (int i = 0; i < 4; ++i)
        #pragma unroll
        for (int j = 0; j < 2; ++j) {
            accn[i][j] = (f32x4){0.f, 0.f, 0.f, 0.f};
            accd[i][j] = (f32x4){0.f, 0.f, 0.f, 0.f};
        }

    // staging coords: 512 threads cover {A: 128 rows, B: 2x128 rows} x 32 cols
    const int crow  = tid >> 2;                 // 0..127
    const int gchk  = tid & 3;
    const int cswz  = (crow >> 1) & 3;
    const int ccols = (gchk ^ cswz) * 8;        // pre-swizzled SOURCE col (B)
    const int aslot = crow * 32 + (gchk ^ cswz) * 8;  // swizzled LDS slot (A)
    const int wbase = wid * 512;                // gload dest: wave chunk (u16)
    const int sq8   = (qd ^ ((r >> 1) & 3)) * 8;

    // EWb window mapping for this thread's row: j = sc - t0 + jbase
    const int jbase = 128 - 64 * (crow >> 6);

    for (int c = 0; c < 12; ++c) {
        const int sc = t0 - 128 + c * 32;
        if (sc < 0 || sc >= T_) continue;   // uniform per block
        __syncthreads();                    // prior compute's ds_reads done
        // stage B: ek rows + ekv rows, 128 each, via gload (swizzled source)
        gload_lds16(&ekT[((size_t)(b * 512) + dh + crow) * 2048 + sc + ccols],
                    &Bkv[wbase]);
        gload_lds16(&ekT[((size_t)(b * 512) + 256 + dh + crow) * 2048 + sc + ccols],
                    &Bkv[4096 + wbase]);
        // stage A: EWb window chunk or zero -> swizzled ds_write
        // (source col UNswizzled gchk*8; dest slot swizzled)
        {
            const int j0 = sc - t0 + jbase;   // mult of 32; window = [0,320)
            uint4 v = (uint4){0u, 0u, 0u, 0u};
            if (j0 >= 0 && j0 < 320)
                v = *(const uint4*)&EWb[(size_t)(t0 + crow) * 320 + j0 + gchk * 8];
            *(uint4*)&Aw[aslot] = v;
        }
        __syncthreads();                    // vmcnt(0) + lgkm drain

        bf16x8 af[4];
        #pragma unroll
        for (int mf = 0; mf < 4; ++mf)
            af[mf] = *(const bf16x8*)&Aw[(th * 64 + mf * 16 + r) * 32 + sq8];
        #pragma unroll
        for (int nf = 0; nf < 2; ++nf) {
            bf16x8 be = *(const bf16x8*)&Bkv[(wn + nf * 16 + r) * 32 + sq8];
            bf16x8 bv = *(const bf16x8*)&Bkv[(128 + wn + nf * 16 + r) * 32 + sq8];
            #pragma unroll
            for (int mf = 0; mf < 4; ++mf) {
                accd[mf][nf] = __builtin_amdgcn_mfma_f32_16x16x32_bf16(af[mf], be, accd[mf][nf], 0, 0, 0);
                accn[mf][nf] = __builtin_amdgcn_mfma_f32_16x16x32_bf16(af[mf], bv, accn[mf][nf], 0, 0, 0);
            }
        }
    }

    // epilogue: y into LDS [t_local][136] then coalesced store to y[b][t][d]
    __syncthreads();
    u16* Ly = sm;    // [128][136]
    #pragma unroll
    for (int nf = 0; nf < 2; ++nf) {
        const int dl = wn + nf * 16 + r;
        const int d  = dh + dl;
        const float skq = Sk[(b << 8) + d];
        const float svq = Sv[(b << 8) + d];
        #pragma unroll
        for (int mf = 0; mf < 4; ++mf) {
            const int ttl = th * 64 + mf * 16 + qd * 4;   // 0..127 local t
            size_t off = ((size_t)(b << 8) + d) * 2048 + t0 + ttl;
            ushort4 sg = *(const ushort4*)&sigqT[off];
            float s4[4] = {bf16_f32(sg.x), bf16_f32(sg.y), bf16_f32(sg.z), bf16_f32(sg.w)};
            #pragma unroll
            for (int reg = 0; reg < 4; ++reg) {
                float y = s4[reg] * (svq + accn[mf][nf][reg]) / (skq + accd[mf][nf][reg]);
                Ly[(ttl + reg) * 136 + dl] = f32_bf16_rne(y);
            }
        }
    }
    __syncthreads();
    {
        const int tl  = tid >> 2;          // 0..127
        const int ds4 = (tid & 3) * 32;    // 0..96
        u16* dst = yTD + ((size_t)b * 2048 + t0 + tl) * 256 + dh + ds4;
        #pragma unroll
        for (int i = 0; i < 4; ++i)
            *(uint4*)&dst[i * 8] = *(const uint4*)&Ly[tl * 136 + ds4 + i * 8];
    }
}

// ---------------------------------------------------------------------------
// K4: out = y @ Wo, single-bf16 both sides.  R10: 128x128 tile, 512 threads
// (8 waves 2Mx4N, wave tile 64x32, acc 32 regs) -- block-steps halve
// (8192->4096), Wo staging traffic halves, 2 gloads/thread/step (was 3).
// Same verified gload_lds + both-sides XOR swizzle pattern.
// ---------------------------------------------------------------------------
__global__ __launch_bounds__(512, 4) void aft_out_mfma(
    const u16* __restrict__ yTD, const u16* __restrict__ Woth,
    float* __restrict__ out)
{
    __shared__ alignas(16) u16 sm[8192];
    u16* As = sm;           // [128][32]
    u16* Bh = sm + 4096;    // [128][32]

    const int tid  = threadIdx.x;        // 0..511
    const int row0 = blockIdx.x * 128;
    const int col0 = blockIdx.y * 128;
    const int lane = tid & 63;
    const int wid  = tid >> 6;           // 0..7
    const int wm   = (wid >> 2) * 64;    // 2 M-groups of 64
    const int wn   = (wid & 3) * 32;     // 4 N-groups of 32
    const int qd   = lane >> 4;
    const int r    = lane & 15;

    f32x4 acc[4][2];
    #pragma unroll
    for (int i = 0; i < 4; ++i)
        #pragma unroll
        for (int j = 0; j < 2; ++j)
            acc[i][j] = (f32x4){0.f, 0.f, 0.f, 0.f};

    const int crow  = tid >> 2;                 // 0..127
    const int gchk  = tid & 3;
    const int cswz  = (crow >> 1) & 3;
    const int ccols = (gchk ^ cswz) * 8;        // pre-swizzled SOURCE col
    const int wbase = wid * 512;                // wave writes LDS rows 16w..16w+15
    const int sq8   = (qd ^ ((r >> 1) & 3)) * 8;

    for (int k0 = 0; k0 < D_; k0 += 32) {
        if (k0) __syncthreads();
        gload_lds16(&yTD[(size_t)(row0 + crow) * 256 + k0 + ccols],
                    &As[wbase]);
        gload_lds16(&Woth[(size_t)(col0 + crow) * 256 + k0 + ccols],
                    &Bh[wbase]);
        __syncthreads();

        bf16x8 af[4];
        #pragma unroll
        for (int mf = 0; mf < 4; ++mf)
            af[mf] = *(const bf16x8*)&As[(wm + mf * 16 + r) * 32 + sq8];
        #pragma unroll
        for (int nf = 0; nf < 2; ++nf) {
            bf16x8 bh = *(const bf16x8*)&Bh[(wn + nf * 16 + r) * 32 + sq8];
            #pragma unroll
            for (int mf = 0; mf < 4; ++mf)
                acc[mf][nf] = __builtin_amdgcn_mfma_f32_16x16x32_bf16(af[mf], bh, acc[mf][nf], 0, 0, 0);
        }
    }

    #pragma unroll
    for (int mf = 0; mf < 4; ++mf)
        #pragma unroll
        for (int nf = 0; nf < 2; ++nf)
            #pragma unroll
            for (int reg = 0; reg < 4; ++reg) {
                int mrow = row0 + wm + mf * 16 + qd * 4 + reg;
                int ncol = col0 + wn + nf * 16 + r;
                out[(size_t)mrow * D_ + ncol] = acc[mf][nf][reg];
            }
}

extern "C" void kernel_launch(void* const* d_in, const int* in_sizes, int n_in,
                              void* d_out, int out_size, void* d_ws, size_t ws_size,
                              hipStream_t stream)
{
    const float* x  = (const float*)d_in[0];
    const float* Wq = (const float*)d_in[1];
    const float* Wk = (const float*)d_in[2];
    const float* Wv = (const float*)d_in[3];
    const float* Wo = (const float*)d_in[4];
    const float* wb = (const float*)d_in[5];
    // window (d_in[6]) is the constant 128, baked in as W_.

    u16* Wth   = (u16*)d_ws;                 // 4*65536 = 262144
    u16* Wkl   = Wth + 262144;               // 65536
    u16* EWb   = Wkl + 65536;                // 655360
    u16* ekT   = EWb + 655360;               // 16777216
    u16* sigqT = ekT + 16777216;             // 8388608
    u16* yTD   = sigqT + 8388608;            // 8388608
    float* Sk  = (float*)(yTD + 8388608);    // 4096
    float* Sv  = Sk + 4096;                  // 4096
    float* Skp = Sv + 4096;                  // 32*8192 = 262144 (1MB)

    aft_split_wT<<<dim3(4, 16), 256, 0, stream>>>(Wq, Wk, Wv, Wo, Wth, Wkl);
    aft_ewb<<<dim3(T_), 320, 0, stream>>>(wb, EWb);
    aft_qkv_mfma<<<dim3(M_ / 64, 4), 256, 0, stream>>>(x, Wth, Wkl, ekT, sigqT, Skp);
    aft_sums2<<<dim3(32), 256, 0, stream>>>(Skp, Sk, Sv);
    aft_band_mfma<<<dim3(T_ / 128, B_ * 2), 512, 0, stream>>>(EWb, ekT, sigqT, Sk, Sv, yTD);
    aft_out_mfma<<<dim3(M_ / 128, 2), 512, 0, stream>>>(yTD, Wth + 3 * 65536, (float*)d_out);
}